// Round 1
// baseline (90962.372 us; speedup 1.0000x reference)
//
#include <hip/hip_runtime.h>
#include <hip/hip_fp16.h>

#define BB 16
#define TT 1024
#define DD 1024
#define SS 512
#define MM 16
#define KK 3072   // 3*D : [x | ctx | h]

#define NBLK 256
#define NTHR 512

// d_out layout (floats): context [0,16384) | alignment [16384, 8404992) | termination [8404992, 8405008)
#define OUT_ALIGN 16384
#define OUT_TERM  8404992

struct KParams {
  const float* x;      // input_h_c (B,T,D)
  const float* mem;    // memory (B,S,D)
  const int*   lens;   // input_lengths (B,)
  const float* W_ih;   // (4D, 2D)
  const float* W_hh;   // (4D, D)
  const float* b_ih;   // (4D,)
  const float* b_hh;   // (4D,)
  const float* Wg_w;   // (48, D)
  const float* Wg_b;   // (48,)
  float* out;
  unsigned* bar;       // barrier counters (zeroed by memset each call)
  float* xc0;          // (B, 3072)
  float* xc1;          // (B, 3072)
};

__device__ __forceinline__ float sigf(float v) { return 1.0f / (1.0f + __expf(-v)); }

__device__ __forceinline__ void grid_barrier(unsigned* bar, unsigned target, int blk) {
  __syncthreads();
  if (threadIdx.x == 0) {
    __threadfence();  // release: make our global stores visible device-wide
    unsigned r = __hip_atomic_fetch_add(&bar[16 + (blk & 15) * 16], 1u,
                                        __ATOMIC_RELAXED, __HIP_MEMORY_SCOPE_AGENT);
    bool setter = false;
    if ((r & 15u) == 15u) {
      unsigned r2 = __hip_atomic_fetch_add(&bar[8], 1u,
                                           __ATOMIC_RELAXED, __HIP_MEMORY_SCOPE_AGENT);
      if ((r2 & 15u) == 15u) {
        __hip_atomic_store(&bar[0], target, __ATOMIC_RELEASE, __HIP_MEMORY_SCOPE_AGENT);
        setter = true;
      }
    }
    if (!setter) {
      while (__hip_atomic_load(&bar[0], __ATOMIC_RELAXED, __HIP_MEMORY_SCOPE_AGENT) < target)
        __builtin_amdgcn_s_sleep(1);
    }
    __builtin_amdgcn_fence(__ATOMIC_ACQUIRE, "agent");  // invalidate stale cached lines
  }
  __syncthreads();
}

__global__ __launch_bounds__(NTHR, 2) void tts_kernel(KParams p) {
  extern __shared__ char smem[];
  float*  Xs    = (float*)smem;                 // [512][20] fp32 = 40960 B
  __half* memsh = (__half*)(smem + 40960);      // [512][64] fp16 = 65536 B

  __shared__ float Ysh[2][16][16];
  __shared__ float phish[48 * 8];
  __shared__ float phi_s[48];
  __shared__ float alsh[16], ksish[16], invbsh[16];
  __shared__ float wsh[512];
  __shared__ float ctxp[8][64];

  const int t    = threadIdx.x;
  const int blk  = blockIdx.x;
  const int jg   = t >> 7;    // [0,4): row group (4 rows each)
  const int ks   = t & 127;   // k-split lane
  const int lane = t & 63;
  const int w64  = t >> 6;    // wave id [0,8)
  const int bbt  = blk & 15;  // batch for S3 (same XCD per batch)
  const int dc   = blk >> 4;  // 64-wide d-chunk for S3

  // ---- load this thread's GEMM weights into registers (stay resident all call) ----
  float wreg[96];
#pragma unroll
  for (int c = 0; c < 6; ++c)
#pragma unroll
    for (int i = 0; i < 4; ++i)
#pragma unroll
      for (int rr = 0; rr < 4; ++rr) {
        int k = c * 512 + i * 128 + ks;
        int r = rr * 1024 + blk * 4 + jg;  // gate rr, d = blk*4 + jg... (row set of this block)
        float wv;
        if (c < 4) wv = p.W_ih[(size_t)r * 2048 + k];
        else       wv = p.W_hh[(size_t)r * 1024 + (k - 2048)];
        wreg[(c * 4 + i) * 4 + rr] = wv;
      }

  // ---- stage memory[bbt, :, dc*64 .. +64) into LDS as fp16 (once) ----
  {
    int dl = t & 63, sp = t >> 6;
    for (int s = sp; s < 512; s += 8)
      memsh[s * 64 + dl] =
          __float2half_rn(p.mem[(size_t)bbt * SS * DD + (size_t)s * DD + dc * 64 + dl]);
  }
  // ---- init XC0 = [x_0 | 0 | 0] ----
  if (t < 64) {
    int d = dc * 64 + t;
    p.xc0[bbt * KK + d]        = p.x[(size_t)bbt * TT * DD + d];
    p.xc0[bbt * KK + 1024 + d] = 0.0f;
    p.xc0[bbt * KK + 2048 + d] = 0.0f;
  }

  float c_val = 0.0f;       // LSTM cell state (threads 0..63 own (b, dl))
  unsigned target = 0;
  float* xc_cur = p.xc0;
  float* xc_nxt = p.xc1;

  grid_barrier(p.bar, ++target, blk);

  for (int tstep = 0; tstep < TT; ++tstep) {
    // ================= S1': gates GEMM + fused LSTM pointwise =================
    float acc[64];
#pragma unroll
    for (int v = 0; v < 64; ++v) acc[v] = 0.0f;

#pragma unroll
    for (int c = 0; c < 6; ++c) {
      {  // stage X chunk: XC[b][c*512 + k] -> Xs[k][b] (b128 writes along b)
        int kl = t & 127, bq = t >> 7;
        const float* src = xc_cur + c * 512;
#pragma unroll
        for (int q = 0; q < 4; ++q) {
          int k = q * 128 + kl;
          float4 v4;
          v4.x = src[(bq * 4 + 0) * KK + k];
          v4.y = src[(bq * 4 + 1) * KK + k];
          v4.z = src[(bq * 4 + 2) * KK + k];
          v4.w = src[(bq * 4 + 3) * KK + k];
          *(float4*)&Xs[k * 20 + bq * 4] = v4;
        }
      }
      __syncthreads();
#pragma unroll
      for (int i = 0; i < 4; ++i) {
        int k = i * 128 + ks;
        float xv[16];
        *(float4*)&xv[0]  = *(float4*)&Xs[k * 20 + 0];
        *(float4*)&xv[4]  = *(float4*)&Xs[k * 20 + 4];
        *(float4*)&xv[8]  = *(float4*)&Xs[k * 20 + 8];
        *(float4*)&xv[12] = *(float4*)&Xs[k * 20 + 12];
#pragma unroll
        for (int rr = 0; rr < 4; ++rr) {
          float wv = wreg[(c * 4 + i) * 4 + rr];
#pragma unroll
          for (int b = 0; b < 16; ++b)
            acc[rr * 16 + b] = __builtin_fmaf(wv, xv[b], acc[rr * 16 + b]);
        }
      }
      __syncthreads();
    }

    // 64-lane butterfly reduction, halving the value set each round
#pragma unroll
    for (int m2 = 0; m2 < 6; ++m2) {
      const int half = 32 >> m2;
      bool up = (lane >> m2) & 1;
#pragma unroll
      for (int i2 = 0; i2 < half; ++i2) {
        float snd = up ? acc[i2] : acc[i2 + half];
        float oth = __shfl_xor(snd, 1 << m2, 64);
        float kp  = up ? acc[i2 + half] : acc[i2];
        acc[i2] = kp + oth;
      }
    }
    {
      int v = __brev((unsigned)lane) >> 26;  // lane holds logical index bitrev6(lane)
      Ysh[w64 & 1][jg * 4 + (v >> 4)][v & 15] = acc[0];
    }
    __syncthreads();

    if (t < 64) {  // pointwise LSTM for (b = t>>2, d = blk*4 + (t&3))
      int b = t >> 2, dl = t & 3, d = blk * 4 + dl;
      float gate[4];
#pragma unroll
      for (int g = 0; g < 4; ++g) {
        int r = g * 1024 + d;
        gate[g] = Ysh[0][dl * 4 + g][b] + Ysh[1][dl * 4 + g][b] + p.b_ih[r] + p.b_hh[r];
      }
      c_val = sigf(gate[1]) * c_val + sigf(gate[0]) * tanhf(gate[2]);
      float hv = sigf(gate[3]) * tanhf(c_val);
      xc_nxt[b * KK + 2048 + d] = hv;
    }
    grid_barrier(p.bar, ++target, blk);

    // ================= S3: attention (phi -> alpha/ksi/beta -> w -> ctx) =================
    const float* hrow = xc_nxt + bbt * KK + 2048;
    if (t < 384) {  // phi partials: m = t>>3 in [0,48), part = t&7
      int m = t >> 3, part = t & 7;
      const float* wg = p.Wg_w + m * 1024 + part * 128;
      const float* hp = hrow + part * 128;
      float s = 0.0f;
#pragma unroll 8
      for (int q = 0; q < 32; ++q) {
        float4 a  = *(const float4*)&wg[q * 4];
        float4 hh = *(const float4*)&hp[q * 4];
        s += a.x * hh.x + a.y * hh.y + a.z * hh.z + a.w * hh.w;
      }
      phish[m * 8 + part] = s;
    }
    __syncthreads();
    if (t < 48) {
      float s = p.Wg_b[t];
#pragma unroll
      for (int pp = 0; pp < 8; ++pp) s += phish[t * 8 + pp];
      phi_s[t] = s;
    }
    __syncthreads();
    if (t == 0) {  // tiny: softmax + exps, serial on one thread
      float mx = -1e30f;
      for (int m = 0; m < 16; ++m) mx = fmaxf(mx, phi_s[32 + m]);
      float e[16], sum = 0.0f;
      for (int m = 0; m < 16; ++m) { e[m] = __expf(phi_s[32 + m] - mx); sum += e[m]; }
      float inv = 1.0f / sum;
      for (int m = 0; m < 16; ++m) alsh[m] = e[m] * inv;
      for (int m = 0; m < 16; ++m) { ksish[m] = __expf(phi_s[m]); invbsh[m] = __expf(-phi_s[16 + m]); }
    }
    __syncthreads();
    {  // w[s] and (last step) termination; F_L(s) = F_R(s-1)
      int s = t;
      float su = (float)s;
      float wv = 0.0f, rv = 0.0f;
#pragma unroll
      for (int m = 0; m < 16; ++m) {
        float a = alsh[m], kk = ksish[m], ib = invbsh[m];
        float Eh = sigf((su + 0.5f - kk) * ib);
        float El = sigf((su - 0.5f - kk) * ib);
        wv += a * (Eh - El);
        rv += a * Eh;
      }
      wsh[s] = wv;
      if (dc == 0) {
        p.out[OUT_ALIGN + ((size_t)bbt * TT + tstep) * SS + s] = wv;
        if (tstep == TT - 1 && s == p.lens[bbt] - 1) p.out[OUT_TERM + bbt] = 1.0f - rv;
      }
    }
    __syncthreads();
    {  // ctx partials from LDS-resident fp16 memory slice
      int dl = t & 63, sp = t >> 6;
      float s = 0.0f;
#pragma unroll 8
      for (int q = 0; q < 64; ++q) {
        int si = sp * 64 + q;
        s = __builtin_fmaf(wsh[si], __half2float(memsh[si * 64 + dl]), s);
      }
      ctxp[sp][dl] = s;
    }
    __syncthreads();
    if (t < 64) {
      float cv = 0.0f;
#pragma unroll
      for (int pp = 0; pp < 8; ++pp) cv += ctxp[pp][t];
      int d = dc * 64 + t;
      xc_nxt[bbt * KK + 1024 + d] = cv;
      if (tstep == TT - 1) p.out[bbt * DD + d] = cv;
    } else if (t < 128) {
      if (tstep + 1 < TT) {  // copy x_{t+1} into next XC
        int dd = t - 64;
        int d = dc * 64 + dd;
        xc_nxt[bbt * KK + d] = p.x[(size_t)bbt * TT * DD + (size_t)(tstep + 1) * DD + d];
      }
    }
    grid_barrier(p.bar, ++target, blk);

    float* tmp = xc_cur; xc_cur = xc_nxt; xc_nxt = tmp;
  }
}

extern "C" void kernel_launch(void* const* d_in, const int* in_sizes, int n_in,
                              void* d_out, int out_size, void* d_ws, size_t ws_size,
                              hipStream_t stream) {
  (void)in_sizes; (void)n_in; (void)out_size; (void)ws_size;
  KParams p;
  p.x    = (const float*)d_in[0];
  p.mem  = (const float*)d_in[1];
  p.lens = (const int*)d_in[2];
  p.W_ih = (const float*)d_in[3];
  p.W_hh = (const float*)d_in[4];
  p.b_ih = (const float*)d_in[5];
  p.b_hh = (const float*)d_in[6];
  p.Wg_w = (const float*)d_in[7];
  p.Wg_b = (const float*)d_in[8];
  p.out  = (float*)d_out;
  p.bar  = (unsigned*)d_ws;
  p.xc0  = (float*)((char*)d_ws + 4096);
  p.xc1  = (float*)((char*)d_ws + 4096 + BB * KK * 4);

  hipMemsetAsync(d_ws, 0, 4096, stream);  // zero barrier counters every call

  const unsigned dynLds = 40960 + 65536;  // Xs + fp16 memory slice
  hipFuncSetAttribute((const void*)tts_kernel, hipFuncAttributeMaxDynamicSharedMemorySize,
                      (int)dynLds);

  void* args[] = { &p };
  hipLaunchCooperativeKernel((const void*)tts_kernel, dim3(NBLK), dim3(NTHR), args, dynLds,
                             stream);
}

// Round 2
// 89110.864 us; speedup vs baseline: 1.0208x; 1.0208x over previous
//
#include <hip/hip_runtime.h>
#include <hip/hip_fp16.h>

#define BB 16
#define TT 1024
#define DD 1024
#define SS 512
#define MM 16
#define KK 3072   // 3*D : [x | ctx | h]

#define NBLK 256
#define NTHR 512

// d_out layout (floats): context [0,16384) | alignment [16384, 8404992) | termination [8404992, 8405008)
#define OUT_ALIGN 16384
#define OUT_TERM  8404992

struct KParams {
  const float* x;      // input_h_c (B,T,D)
  const float* mem;    // memory (B,S,D)
  const int*   lens;   // input_lengths (B,)
  const float* W_ih;   // (4D, 2D)
  const float* W_hh;   // (4D, D)
  const float* b_ih;   // (4D,)
  const float* b_hh;   // (4D,)
  const float* Wg_w;   // (48, D)
  const float* Wg_b;   // (48,)
  float* out;
  unsigned* bar;       // barrier counters (zeroed by memset each call)
  float* xc0;          // (B, 3072)
  float* xc1;          // (B, 3072)
};

__device__ __forceinline__ float sigf(float v) { return 1.0f / (1.0f + __expf(-v)); }

__device__ __forceinline__ void grid_barrier(unsigned* bar, unsigned target, int blk) {
  __syncthreads();
  if (threadIdx.x == 0) {
    __threadfence();  // release: make our global stores visible device-wide
    unsigned r = __hip_atomic_fetch_add(&bar[16 + (blk & 15) * 16], 1u,
                                        __ATOMIC_RELAXED, __HIP_MEMORY_SCOPE_AGENT);
    bool setter = false;
    if ((r & 15u) == 15u) {
      unsigned r2 = __hip_atomic_fetch_add(&bar[8], 1u,
                                           __ATOMIC_RELAXED, __HIP_MEMORY_SCOPE_AGENT);
      if ((r2 & 15u) == 15u) {
        __hip_atomic_store(&bar[0], target, __ATOMIC_RELEASE, __HIP_MEMORY_SCOPE_AGENT);
        setter = true;
      }
    }
    if (!setter) {
      while (__hip_atomic_load(&bar[0], __ATOMIC_RELAXED, __HIP_MEMORY_SCOPE_AGENT) < target)
        __builtin_amdgcn_s_sleep(1);
    }
    __builtin_amdgcn_fence(__ATOMIC_ACQUIRE, "agent");  // invalidate stale cached lines
  }
  __syncthreads();
}

// amdgpu_waves_per_eu(2,2): pin occupancy to 2 waves/SIMD so the allocator gets the full
// 256-VGPR budget. R1 evidence: default heuristic chose 128 VGPRs and spilled wreg[96]+acc[64]
// to scratch -> 125 GB/dispatch of HBM spill traffic (87 ms, VALUBusy 10.7%).
__global__ __launch_bounds__(NTHR)
__attribute__((amdgpu_waves_per_eu(2, 2)))
void tts_kernel(KParams p) {
  extern __shared__ char smem[];
  float*  Xs    = (float*)smem;                 // [512][20] fp32 = 40960 B
  __half* memsh = (__half*)(smem + 40960);      // [512][64] fp16 = 65536 B

  __shared__ float Ysh[2][16][16];
  __shared__ float phish[48 * 8];
  __shared__ float phi_s[48];
  __shared__ float alsh[16], ksish[16], invbsh[16];
  __shared__ float wsh[512];
  __shared__ float ctxp[8][64];

  const int t    = threadIdx.x;
  const int blk  = blockIdx.x;
  const int jg   = t >> 7;    // [0,4): row group (4 rows each)
  const int ks   = t & 127;   // k-split lane
  const int lane = t & 63;
  const int w64  = t >> 6;    // wave id [0,8)
  const int bbt  = blk & 15;  // batch for S3 (same XCD per batch)
  const int dc   = blk >> 4;  // 64-wide d-chunk for S3

  // ---- load this thread's GEMM weights into registers (stay resident all call) ----
  float wreg[96];
#pragma unroll
  for (int c = 0; c < 6; ++c)
#pragma unroll
    for (int i = 0; i < 4; ++i)
#pragma unroll
      for (int rr = 0; rr < 4; ++rr) {
        int k = c * 512 + i * 128 + ks;
        int r = rr * 1024 + blk * 4 + jg;  // gate rr, d = blk*4 + jg
        float wv;
        if (c < 4) wv = p.W_ih[(size_t)r * 2048 + k];
        else       wv = p.W_hh[(size_t)r * 1024 + (k - 2048)];
        wreg[(c * 4 + i) * 4 + rr] = wv;
      }

  // ---- stage memory[bbt, :, dc*64 .. +64) into LDS as fp16 (once) ----
  {
    int dl = t & 63, sp = t >> 6;
    for (int s = sp; s < 512; s += 8)
      memsh[s * 64 + dl] =
          __float2half_rn(p.mem[(size_t)bbt * SS * DD + (size_t)s * DD + dc * 64 + dl]);
  }
  // ---- init XC0 = [x_0 | 0 | 0] ----
  if (t < 64) {
    int d = dc * 64 + t;
    p.xc0[bbt * KK + d]        = p.x[(size_t)bbt * TT * DD + d];
    p.xc0[bbt * KK + 1024 + d] = 0.0f;
    p.xc0[bbt * KK + 2048 + d] = 0.0f;
  }

  float c_val = 0.0f;       // LSTM cell state (threads 0..63 own (b, dl))
  unsigned target = 0;
  float* xc_cur = p.xc0;
  float* xc_nxt = p.xc1;

  grid_barrier(p.bar, ++target, blk);

  for (int tstep = 0; tstep < TT; ++tstep) {
    // ================= S1': gates GEMM + fused LSTM pointwise =================
    float acc[64];
#pragma unroll
    for (int v = 0; v < 64; ++v) acc[v] = 0.0f;

#pragma unroll
    for (int c = 0; c < 6; ++c) {
      {  // stage X chunk: XC[b][c*512 + k] -> Xs[k][b] (b128 writes along b)
        int kl = t & 127, bq = t >> 7;
        const float* src = xc_cur + c * 512;
#pragma unroll
        for (int q = 0; q < 4; ++q) {
          int k = q * 128 + kl;
          float4 v4;
          v4.x = src[(bq * 4 + 0) * KK + k];
          v4.y = src[(bq * 4 + 1) * KK + k];
          v4.z = src[(bq * 4 + 2) * KK + k];
          v4.w = src[(bq * 4 + 3) * KK + k];
          *(float4*)&Xs[k * 20 + bq * 4] = v4;
        }
      }
      __syncthreads();
#pragma unroll
      for (int i = 0; i < 4; ++i) {
        int k = i * 128 + ks;
        // process 4 batches at a time: keeps only one float4 of X live
#pragma unroll
        for (int bq4 = 0; bq4 < 4; ++bq4) {
          float4 xv = *(float4*)&Xs[k * 20 + bq4 * 4];
#pragma unroll
          for (int rr = 0; rr < 4; ++rr) {
            float wv = wreg[(c * 4 + i) * 4 + rr];
            acc[rr * 16 + bq4 * 4 + 0] = __builtin_fmaf(wv, xv.x, acc[rr * 16 + bq4 * 4 + 0]);
            acc[rr * 16 + bq4 * 4 + 1] = __builtin_fmaf(wv, xv.y, acc[rr * 16 + bq4 * 4 + 1]);
            acc[rr * 16 + bq4 * 4 + 2] = __builtin_fmaf(wv, xv.z, acc[rr * 16 + bq4 * 4 + 2]);
            acc[rr * 16 + bq4 * 4 + 3] = __builtin_fmaf(wv, xv.w, acc[rr * 16 + bq4 * 4 + 3]);
          }
        }
      }
      __syncthreads();
    }

    // 64-lane butterfly reduction, halving the value set each round
#pragma unroll
    for (int m2 = 0; m2 < 6; ++m2) {
      const int half = 32 >> m2;
      bool up = (lane >> m2) & 1;
#pragma unroll
      for (int i2 = 0; i2 < half; ++i2) {
        float snd = up ? acc[i2] : acc[i2 + half];
        float oth = __shfl_xor(snd, 1 << m2, 64);
        float kp  = up ? acc[i2 + half] : acc[i2];
        acc[i2] = kp + oth;
      }
    }
    {
      int v = __brev((unsigned)lane) >> 26;  // lane holds logical index bitrev6(lane)
      Ysh[w64 & 1][jg * 4 + (v >> 4)][v & 15] = acc[0];
    }
    __syncthreads();

    if (t < 64) {  // pointwise LSTM for (b = t>>2, d = blk*4 + (t&3))
      int b = t >> 2, dl = t & 3, d = blk * 4 + dl;
      float gate[4];
#pragma unroll
      for (int g = 0; g < 4; ++g) {
        int r = g * 1024 + d;
        gate[g] = Ysh[0][dl * 4 + g][b] + Ysh[1][dl * 4 + g][b] + p.b_ih[r] + p.b_hh[r];
      }
      c_val = sigf(gate[1]) * c_val + sigf(gate[0]) * tanhf(gate[2]);
      float hv = sigf(gate[3]) * tanhf(c_val);
      xc_nxt[b * KK + 2048 + d] = hv;
    }
    grid_barrier(p.bar, ++target, blk);

    // ================= S3: attention (phi -> alpha/ksi/beta -> w -> ctx) =================
    const float* hrow = xc_nxt + bbt * KK + 2048;
    if (t < 384) {  // phi partials: m = t>>3 in [0,48), part = t&7
      int m = t >> 3, part = t & 7;
      const float* wg = p.Wg_w + m * 1024 + part * 128;
      const float* hp = hrow + part * 128;
      float s = 0.0f;
#pragma unroll 8
      for (int q = 0; q < 32; ++q) {
        float4 a  = *(const float4*)&wg[q * 4];
        float4 hh = *(const float4*)&hp[q * 4];
        s += a.x * hh.x + a.y * hh.y + a.z * hh.z + a.w * hh.w;
      }
      phish[m * 8 + part] = s;
    }
    __syncthreads();
    if (t < 48) {
      float s = p.Wg_b[t];
#pragma unroll
      for (int pp = 0; pp < 8; ++pp) s += phish[t * 8 + pp];
      phi_s[t] = s;
    }
    __syncthreads();
    if (t == 0) {  // tiny: softmax + exps, serial on one thread
      float mx = -1e30f;
      for (int m = 0; m < 16; ++m) mx = fmaxf(mx, phi_s[32 + m]);
      float e[16], sum = 0.0f;
      for (int m = 0; m < 16; ++m) { e[m] = __expf(phi_s[32 + m] - mx); sum += e[m]; }
      float inv = 1.0f / sum;
      for (int m = 0; m < 16; ++m) alsh[m] = e[m] * inv;
      for (int m = 0; m < 16; ++m) { ksish[m] = __expf(phi_s[m]); invbsh[m] = __expf(-phi_s[16 + m]); }
    }
    __syncthreads();
    {  // w[s] and (last step) termination; F_L(s) = F_R(s-1)
      int s = t;
      float su = (float)s;
      float wv = 0.0f, rv = 0.0f;
#pragma unroll
      for (int m = 0; m < 16; ++m) {
        float a = alsh[m], kk = ksish[m], ib = invbsh[m];
        float Eh = sigf((su + 0.5f - kk) * ib);
        float El = sigf((su - 0.5f - kk) * ib);
        wv += a * (Eh - El);
        rv += a * Eh;
      }
      wsh[s] = wv;
      if (dc == 0) {
        p.out[OUT_ALIGN + ((size_t)bbt * TT + tstep) * SS + s] = wv;
        if (tstep == TT - 1 && s == p.lens[bbt] - 1) p.out[OUT_TERM + bbt] = 1.0f - rv;
      }
    }
    __syncthreads();
    {  // ctx partials from LDS-resident fp16 memory slice
      int dl = t & 63, sp = t >> 6;
      float s = 0.0f;
#pragma unroll 8
      for (int q = 0; q < 64; ++q) {
        int si = sp * 64 + q;
        s = __builtin_fmaf(wsh[si], __half2float(memsh[si * 64 + dl]), s);
      }
      ctxp[sp][dl] = s;
    }
    __syncthreads();
    if (t < 64) {
      float cv = 0.0f;
#pragma unroll
      for (int pp = 0; pp < 8; ++pp) cv += ctxp[pp][t];
      int d = dc * 64 + t;
      xc_nxt[bbt * KK + 1024 + d] = cv;
      if (tstep == TT - 1) p.out[bbt * DD + d] = cv;
    } else if (t < 128) {
      if (tstep + 1 < TT) {  // copy x_{t+1} into next XC
        int dd = t - 64;
        int d = dc * 64 + dd;
        xc_nxt[bbt * KK + d] = p.x[(size_t)bbt * TT * DD + (size_t)(tstep + 1) * DD + d];
      }
    }
    grid_barrier(p.bar, ++target, blk);

    float* tmp = xc_cur; xc_cur = xc_nxt; xc_nxt = tmp;
  }
}

extern "C" void kernel_launch(void* const* d_in, const int* in_sizes, int n_in,
                              void* d_out, int out_size, void* d_ws, size_t ws_size,
                              hipStream_t stream) {
  (void)in_sizes; (void)n_in; (void)out_size; (void)ws_size;
  KParams p;
  p.x    = (const float*)d_in[0];
  p.mem  = (const float*)d_in[1];
  p.lens = (const int*)d_in[2];
  p.W_ih = (const float*)d_in[3];
  p.W_hh = (const float*)d_in[4];
  p.b_ih = (const float*)d_in[5];
  p.b_hh = (const float*)d_in[6];
  p.Wg_w = (const float*)d_in[7];
  p.Wg_b = (const float*)d_in[8];
  p.out  = (float*)d_out;
  p.bar  = (unsigned*)d_ws;
  p.xc0  = (float*)((char*)d_ws + 4096);
  p.xc1  = (float*)((char*)d_ws + 4096 + BB * KK * 4);

  hipMemsetAsync(d_ws, 0, 4096, stream);  // zero barrier counters every call

  const unsigned dynLds = 40960 + 65536;  // Xs + fp16 memory slice
  hipFuncSetAttribute((const void*)tts_kernel, hipFuncAttributeMaxDynamicSharedMemorySize,
                      (int)dynLds);

  void* args[] = { &p };
  hipLaunchCooperativeKernel((const void*)tts_kernel, dim3(NBLK), dim3(NTHR), args, dynLds,
                             stream);
}

// Round 3
// 40288.602 us; speedup vs baseline: 2.2578x; 2.2118x over previous
//
#include <hip/hip_runtime.h>
#include <hip/hip_fp16.h>

#define BB 16
#define TT 1024
#define DD 1024
#define SS 512
#define KK 3072   // [x | ctx | h]

#define NBLK 256
#define NTHR 512

// d_out layout (floats): context [0,16384) | alignment [16384, 8404992) | termination [8404992,+16)
#define OUT_ALIGN 16384
#define OUT_TERM  8404992

typedef __attribute__((ext_vector_type(8))) short short8;    // 8 bf16 (4 VGPRs)
typedef __attribute__((ext_vector_type(4))) float floatx4;   // MFMA C/D

struct KParams {
  const float* x;      // (B,T,D) fp32
  const float* mem;    // (B,S,D) fp32
  const int*   lens;
  const float* W_ih;   // (4D, 2D)
  const float* W_hh;   // (4D, D)
  const float* b_ih;
  const float* b_hh;
  const float* Wg_w;   // (48, D)
  const float* Wg_b;
  float* out;
  unsigned* bar;
  unsigned short* xc0;  // (B, 3072) bf16 recurrent state [x|ctx|h]
  unsigned short* xc1;
  float* gphi;          // (B, 48)
};

__device__ __forceinline__ float sigf(float v) { return 1.0f / (1.0f + __expf(-v)); }

__device__ __forceinline__ unsigned short f2bf(float f) {  // RNE fp32->bf16
  unsigned u = __float_as_uint(f);
  return (unsigned short)((u + 0x7FFFu + ((u >> 16) & 1u)) >> 16);
}
__device__ __forceinline__ float bf2f(unsigned short h) {
  return __uint_as_float(((unsigned)h) << 16);
}

__device__ __forceinline__ void grid_barrier(unsigned* bar, unsigned target, int blk) {
  __syncthreads();
  if (threadIdx.x == 0) {
    __threadfence();  // release our global stores device-wide
    unsigned r = __hip_atomic_fetch_add(&bar[16 + (blk & 15) * 16], 1u,
                                        __ATOMIC_RELAXED, __HIP_MEMORY_SCOPE_AGENT);
    bool setter = false;
    if ((r & 15u) == 15u) {
      unsigned r2 = __hip_atomic_fetch_add(&bar[8], 1u,
                                           __ATOMIC_RELAXED, __HIP_MEMORY_SCOPE_AGENT);
      if ((r2 & 15u) == 15u) {
        __hip_atomic_store(&bar[0], target, __ATOMIC_RELEASE, __HIP_MEMORY_SCOPE_AGENT);
        setter = true;
      }
    }
    if (!setter) {
      while (__hip_atomic_load(&bar[0], __ATOMIC_RELAXED, __HIP_MEMORY_SCOPE_AGENT) < target)
        __builtin_amdgcn_s_sleep(1);
    }
    __builtin_amdgcn_fence(__ATOMIC_ACQUIRE, "agent");  // invalidate stale caches
  }
  __syncthreads();
}

// Register budget is the whole game (R1/R2: 128-VGPR cap + ~220 demand = spill = 123 GB
// HBM traffic). This version: bf16 B-frags 48 VGPR + A-frag window 24 + acc 8 + temps -> ~110.
__global__ __launch_bounds__(NTHR) void tts_kernel(KParams p) {
  extern __shared__ char smem[];
  __half* memsh = (__half*)smem;  // [512][64] fp16, 64 KiB

  __shared__ float redC[8 * 4 * 65 + 4];  // wave-partial C tiles, padded rows
  __shared__ float phpart[3][128];
  __shared__ float ph2[3][16];
  __shared__ float phi_s[48];
  __shared__ float alsh[16], ksish[16], invbsh[16];
  __shared__ float wsh[512];
  __shared__ float ctxp[8][64];

  const int t    = threadIdx.x;
  const int blk  = blockIdx.x;
  const int lane = t & 63;
  const int w    = t >> 6;     // wave id [0,8): owns K-slice [w*384, w*384+384)
  const int bbt  = blk & 15;   // batch this block serves in attention/ctx
  const int dc   = blk >> 4;   // 64-wide d-chunk (ctx) / m-triple (phi) / x-copy segment

  // ---- one-time: B-fragments (weights) into registers as bf16 ----
  // C-tile: m=batch, n in [0,16): row r(n) = (n&3)*1024 + blk*4 + (n>>2)
  short8 bfr[12];
  {
    const int n = lane & 15;
    const int r = (n & 3) * 1024 + blk * 4 + (n >> 2);
    const int q = lane >> 4;
#pragma unroll
    for (int ki = 0; ki < 12; ++ki) {
      short8 v;
      const int k0 = w * 384 + ki * 32 + q * 8;
#pragma unroll
      for (int j = 0; j < 8; ++j) {
        int k = k0 + j;
        float wv = (k < 2048) ? p.W_ih[(size_t)r * 2048 + k]
                              : p.W_hh[(size_t)r * 1024 + (k - 2048)];
        v[j] = (short)f2bf(wv);
      }
      bfr[ki] = v;
    }
  }
  // ---- one-time: biases for this block's 4 d-dims ----
  float biasreg[4] = {0.f, 0.f, 0.f, 0.f};
  if (t < 64) {
    int dl = t & 3;
#pragma unroll
    for (int g = 0; g < 4; ++g) {
      int r = g * 1024 + blk * 4 + dl;
      biasreg[g] = p.b_ih[r] + p.b_hh[r];
    }
  }
  // ---- one-time: memory[bbt, :, dc*64..+64) -> LDS fp16 ----
  {
    int dl = t & 63, sp = t >> 6;
    for (int s = sp; s < 512; s += 8)
      memsh[s * 64 + dl] =
          __float2half_rn(p.mem[(size_t)bbt * SS * DD + (size_t)s * DD + dc * 64 + dl]);
  }
  // ---- one-time: xc0 = [x_0 | 0 | 0] (block (bbt,dc) covers k = dc*64..+64) ----
  if (t < 64) {
    int k = dc * 64 + t;
    p.xc0[bbt * KK + k]        = f2bf(p.x[(size_t)bbt * TT * DD + k]);
    p.xc0[bbt * KK + 1024 + k] = 0;
    p.xc0[bbt * KK + 2048 + k] = 0;
  }

  float c_val = 0.0f;  // LSTM cell state: thread t<64 owns (b=t>>2, d=blk*4+(t&3))
  unsigned target = 0;
  unsigned short* xc_cur = p.xc0;
  unsigned short* xc_nxt = p.xc1;
  const int aoff = (lane & 15) * KK + w * 384 + (lane >> 4) * 8;  // A-frag base offset

  grid_barrier(p.bar, ++target, blk);

  for (int tstep = 0; tstep < TT; ++tstep) {
    // ================= Phase A: gates MFMA + LSTM pointwise =================
    {
      const unsigned short* xb = xc_cur + aoff;
      floatx4 a0 = {0.f, 0.f, 0.f, 0.f}, a1 = {0.f, 0.f, 0.f, 0.f};
      // two 6-frag batches keep transient A regs at 24
      short8 af[6];
#pragma unroll
      for (int ki = 0; ki < 6; ++ki) af[ki] = *(const short8*)(xb + ki * 32);
#pragma unroll
      for (int ki = 0; ki < 6; ki += 2) {
        a0 = __builtin_amdgcn_mfma_f32_16x16x32_bf16(af[ki], bfr[ki], a0, 0, 0, 0);
        a1 = __builtin_amdgcn_mfma_f32_16x16x32_bf16(af[ki + 1], bfr[ki + 1], a1, 0, 0, 0);
      }
#pragma unroll
      for (int ki = 0; ki < 6; ++ki) af[ki] = *(const short8*)(xb + (ki + 6) * 32);
#pragma unroll
      for (int ki = 0; ki < 6; ki += 2) {
        a0 = __builtin_amdgcn_mfma_f32_16x16x32_bf16(af[ki], bfr[ki + 6], a0, 0, 0, 0);
        a1 = __builtin_amdgcn_mfma_f32_16x16x32_bf16(af[ki + 1], bfr[ki + 7], a1, 0, 0, 0);
      }
      a0 += a1;
      // C layout: batch b = (lane>>4)*4 + reg, row-n = lane&15
#pragma unroll
      for (int reg = 0; reg < 4; ++reg)
        redC[(w * 4 + reg) * 65 + lane] = a0[reg];
    }
    __syncthreads();
    if (t < 64) {  // pointwise LSTM for (b = t>>2, dl = t&3)
      int b = t >> 2, dl = t & 3;
      float gate[4];
#pragma unroll
      for (int g = 0; g < 4; ++g) {
        int ls = (b >> 2) * 16 + (dl * 4 + g);
        float s = biasreg[g];
#pragma unroll
        for (int w2 = 0; w2 < 8; ++w2) s += redC[(w2 * 4 + (b & 3)) * 65 + ls];
        gate[g] = s;
      }
      c_val = sigf(gate[1]) * c_val + sigf(gate[0]) * tanhf(gate[2]);
      float hv = sigf(gate[3]) * tanhf(c_val);
      xc_nxt[b * KK + 2048 + blk * 4 + dl] = f2bf(hv);
    }
    grid_barrier(p.bar, ++target, blk);

    // ================= Phase B: phi (each block: batch bbt, m-triple dc) + x-copy ==========
    {
      if (t < 384) {
        int mm = t >> 7, kp = t & 127;
        int m = dc * 3 + mm;
        const unsigned short* hp = xc_nxt + bbt * KK + 2048 + kp * 8;
        const float* wg = p.Wg_w + m * 1024 + kp * 8;
        float s = 0.f;
#pragma unroll
        for (int j = 0; j < 8; ++j) s += bf2f(hp[j]) * wg[j];
        phpart[mm][kp] = s;
      }
      if (t < 64 && tstep + 1 < TT) {  // stage x_{t+1} into xc_nxt (bf16)
        int k = dc * 64 + t;
        xc_nxt[bbt * KK + k] =
            f2bf(p.x[(size_t)bbt * TT * DD + (size_t)(tstep + 1) * DD + k]);
      }
      __syncthreads();
      if (t < 48) {
        int mm = t >> 4, seg = t & 15;
        float s = 0.f;
#pragma unroll
        for (int i = 0; i < 8; ++i) s += phpart[mm][seg * 8 + i];
        ph2[mm][seg] = s;
      }
      __syncthreads();
      if (t < 3) {
        float s = p.Wg_b[dc * 3 + t];
#pragma unroll
        for (int i = 0; i < 16; ++i) s += ph2[t][i];
        p.gphi[bbt * 48 + dc * 3 + t] = s;
      }
    }
    grid_barrier(p.bar, ++target, blk);

    // ================= Phase C: window w -> ctx =================
    if (t < 48) phi_s[t] = p.gphi[bbt * 48 + t];
    __syncthreads();
    if (t == 0) {  // softmax(alpha) + exps (tiny, serial)
      float mx = -1e30f;
      for (int m = 0; m < 16; ++m) mx = fmaxf(mx, phi_s[32 + m]);
      float e[16], sum = 0.f;
      for (int m = 0; m < 16; ++m) { e[m] = __expf(phi_s[32 + m] - mx); sum += e[m]; }
      float inv = 1.0f / sum;
      for (int m = 0; m < 16; ++m) alsh[m] = e[m] * inv;
      for (int m = 0; m < 16; ++m) {
        ksish[m]  = __expf(phi_s[m]);
        invbsh[m] = __expf(-phi_s[16 + m]);
      }
    }
    __syncthreads();
    {  // w[s] for s = t; alignment + termination from dc==0 blocks
      float su = (float)t;
      float wv = 0.f, rv = 0.f;
#pragma unroll
      for (int m = 0; m < 16; ++m) {
        float a = alsh[m], kk = ksish[m], ib = invbsh[m];
        float Eh = sigf((su + 0.5f - kk) * ib);
        float El = sigf((su - 0.5f - kk) * ib);
        wv += a * (Eh - El);
        rv += a * Eh;
      }
      wsh[t] = wv;
      if (dc == 0) {
        p.out[OUT_ALIGN + ((size_t)bbt * TT + tstep) * SS + t] = wv;
        if (tstep == TT - 1 && t == p.lens[bbt] - 1) p.out[OUT_TERM + bbt] = 1.0f - rv;
      }
    }
    __syncthreads();
    {  // ctx partials from LDS fp16 memory slice
      int dl = t & 63, sp = t >> 6;
      float s = 0.f;
#pragma unroll 8
      for (int q = 0; q < 64; ++q) {
        int si = sp * 64 + q;
        s = __builtin_fmaf(wsh[si], __half2float(memsh[si * 64 + dl]), s);
      }
      ctxp[sp][dl] = s;
    }
    __syncthreads();
    if (t < 64) {
      float cv = 0.f;
#pragma unroll
      for (int pp = 0; pp < 8; ++pp) cv += ctxp[pp][t];
      xc_nxt[bbt * KK + 1024 + dc * 64 + t] = f2bf(cv);
      if (tstep == TT - 1) p.out[bbt * DD + dc * 64 + t] = cv;
    }
    grid_barrier(p.bar, ++target, blk);

    unsigned short* tmp = xc_cur; xc_cur = xc_nxt; xc_nxt = tmp;
  }
}

extern "C" void kernel_launch(void* const* d_in, const int* in_sizes, int n_in,
                              void* d_out, int out_size, void* d_ws, size_t ws_size,
                              hipStream_t stream) {
  (void)in_sizes; (void)n_in; (void)out_size; (void)ws_size;
  KParams p;
  p.x    = (const float*)d_in[0];
  p.mem  = (const float*)d_in[1];
  p.lens = (const int*)d_in[2];
  p.W_ih = (const float*)d_in[3];
  p.W_hh = (const float*)d_in[4];
  p.b_ih = (const float*)d_in[5];
  p.b_hh = (const float*)d_in[6];
  p.Wg_w = (const float*)d_in[7];
  p.Wg_b = (const float*)d_in[8];
  p.out  = (float*)d_out;
  p.bar  = (unsigned*)d_ws;
  p.xc0  = (unsigned short*)((char*)d_ws + 4096);
  p.xc1  = (unsigned short*)((char*)d_ws + 4096 + BB * KK * 2);
  p.gphi = (float*)((char*)d_ws + 4096 + 2 * BB * KK * 2);

  hipMemsetAsync(d_ws, 0, 4096, stream);  // zero barrier counters every call

  const unsigned dynLds = 65536;  // fp16 memory slice
  hipFuncSetAttribute((const void*)tts_kernel, hipFuncAttributeMaxDynamicSharedMemorySize,
                      (int)dynLds);

  void* args[] = { &p };
  hipLaunchCooperativeKernel((const void*)tts_kernel, dim3(NBLK), dim3(NTHR), args, dynLds,
                             stream);
}

// Round 4
// 19850.960 us; speedup vs baseline: 4.5823x; 2.0296x over previous
//
#include <hip/hip_runtime.h>
#include <hip/hip_fp16.h>

#define BB 16
#define TT 1024
#define DD 1024
#define SS 512
#define KK 3072   // [x | ctx | h]

#define NBLK 256
#define NTHR 512

// d_out layout (floats): context [0,16384) | alignment [16384, 8404992) | termination [8404992,+16)
#define OUT_ALIGN 16384
#define OUT_TERM  8404992

typedef __attribute__((ext_vector_type(8))) short short8;     // 8 bf16 (4 VGPRs)
typedef __attribute__((ext_vector_type(4))) float floatx4;    // MFMA C/D
typedef __attribute__((ext_vector_type(2))) _Float16 half2v;  // v_dot2 operand

struct KParams {
  const float* x;      // (B,T,D) fp32
  const float* mem;    // (B,S,D) fp32
  const int*   lens;
  const float* W_ih;   // (4D, 2D)
  const float* W_hh;   // (4D, D)
  const float* b_ih;
  const float* b_hh;
  const float* Wg_w;   // (48, D)
  const float* Wg_b;
  float* out;
  unsigned* bar;
  unsigned short* xc0;  // (B, 3072) bf16 recurrent state [x|ctx|h]
  unsigned short* xc1;
};

__device__ __forceinline__ float sigf(float v) { return 1.0f / (1.0f + __expf(-v)); }

__device__ __forceinline__ unsigned short f2bf(float f) {  // RNE fp32->bf16
  unsigned u = __float_as_uint(f);
  return (unsigned short)((u + 0x7FFFu + ((u >> 16) & 1u)) >> 16);
}
__device__ __forceinline__ float bf2f(unsigned short h) {
  return __uint_as_float(((unsigned)h) << 16);
}
__device__ __forceinline__ unsigned pack2bf(float a, float b) {
  return (unsigned)f2bf(a) | ((unsigned)f2bf(b) << 16);
}

// Coherent (cross-XCD) accessors: agent-scope relaxed atomics carry the sc cache-policy
// bits -> rendezvous at the coherence point, no buffer_wbl2/buffer_inv fences needed.
__device__ __forceinline__ void cstore_u32(unsigned* p2, unsigned v) {
  __hip_atomic_store(p2, v, __ATOMIC_RELAXED, __HIP_MEMORY_SCOPE_AGENT);
}
__device__ __forceinline__ unsigned cload_u32(const unsigned* p2) {
  return __hip_atomic_load(p2, __ATOMIC_RELAXED, __HIP_MEMORY_SCOPE_AGENT);
}
__device__ __forceinline__ unsigned long long cload_u64(const unsigned long long* p2) {
  return __hip_atomic_load(p2, __ATOMIC_RELAXED, __HIP_MEMORY_SCOPE_AGENT);
}

// Fence-free grid barrier. Ordering contract: all coherent data stores were issued before the
// caller's __syncthreads() (which drains each wave's vmcnt before s_barrier), so arrival
// implies data is at the coherence point. Monotonic epochs -> no counter resets.
__device__ __forceinline__ void grid_barrier(unsigned* bar, unsigned ep, int blk) {
  __syncthreads();
  if (threadIdx.x == 0) {
    unsigned r = __hip_atomic_fetch_add(&bar[32 + (blk & 7) * 32], 1u,
                                        __ATOMIC_RELAXED, __HIP_MEMORY_SCOPE_AGENT);
    if ((r & 31u) == 31u)
      __hip_atomic_fetch_add(&bar[0], 1u, __ATOMIC_RELAXED, __HIP_MEMORY_SCOPE_AGENT);
    while (__hip_atomic_load(&bar[0], __ATOMIC_RELAXED, __HIP_MEMORY_SCOPE_AGENT) < 8u * ep)
      __builtin_amdgcn_s_sleep(2);
  }
  asm volatile("" ::: "memory");
  __syncthreads();
}

__global__ __launch_bounds__(NTHR) void tts_kernel(KParams p) {
  extern __shared__ char smem[];
  half2v* memsh2 = (half2v*)smem;  // [256 s-pairs][64 d] fp16x2, 64 KiB

  __shared__ float redC[8 * 4 * 65 + 4];  // wave-partial C tiles
  __shared__ float hshA[64];              // phase-A h staging for packed stores
  __shared__ unsigned hshu[512];          // phase-C h (bf16x2) for phi
  __shared__ float php[384];
  __shared__ float phi_s[48];
  __shared__ float alsh[16], ksish[16], invbsh[16];
  __shared__ float Rsh[513];              // R(s) = sum_m alpha*F_R(s), s=-1..511
  __shared__ half2v wsh2[256];            // w(s) packed in s-pairs
  __shared__ float ctxp[8][64];
  __shared__ float ctxf[64];

  const int t    = threadIdx.x;
  const int blk  = blockIdx.x;
  const int lane = t & 63;
  const int w    = t >> 6;     // wave id [0,8): K-slice [w*384, +384)
  const int bbt  = blk & 15;   // batch this block serves in phase C
  const int dc   = blk >> 4;   // 64-wide d-chunk for ctx / x-copy

  // ---- one-time: B-fragments (weights) into registers as bf16 ----
  short8 bfr[12];
  {
    const int n = lane & 15;
    const int r = (n & 3) * 1024 + blk * 4 + (n >> 2);
    const int q = lane >> 4;
#pragma unroll
    for (int ki = 0; ki < 12; ++ki) {
      short8 v;
      const int k0 = w * 384 + ki * 32 + q * 8;
#pragma unroll
      for (int j = 0; j < 8; ++j) {
        int k = k0 + j;
        float wv = (k < 2048) ? p.W_ih[(size_t)r * 2048 + k]
                              : p.W_hh[(size_t)r * 1024 + (k - 2048)];
        v[j] = (short)f2bf(wv);
      }
      bfr[ki] = v;
    }
  }
  // ---- one-time: biases ----
  float biasreg[4] = {0.f, 0.f, 0.f, 0.f};
  if (t < 64) {
    int dl = t & 3;
#pragma unroll
    for (int g = 0; g < 4; ++g) {
      int r = g * 1024 + blk * 4 + dl;
      biasreg[g] = p.b_ih[r] + p.b_hh[r];
    }
  }
  // ---- one-time: memory[bbt, :, dc*64..+64) -> LDS as half2 s-pairs ----
  {
    int dl = t & 63, sp = t >> 6;
    for (int pr = sp; pr < 256; pr += 8) {
      const float* mp = p.mem + (size_t)bbt * SS * DD + (size_t)(2 * pr) * DD + dc * 64 + dl;
      half2v v;
      v.x = (_Float16)mp[0];
      v.y = (_Float16)mp[DD];
      memsh2[pr * 64 + dl] = v;
    }
  }
  // ---- one-time: xc0 = [x_0 | 0 | 0] via coherent packed stores ----
  if (t < 32) {
    int k = dc * 64 + 2 * t;
    const float* xs = p.x + (size_t)bbt * TT * DD + k;
    cstore_u32((unsigned*)(p.xc0 + bbt * KK + k), pack2bf(xs[0], xs[1]));
    cstore_u32((unsigned*)(p.xc0 + bbt * KK + 1024 + k), 0u);
    cstore_u32((unsigned*)(p.xc0 + bbt * KK + 2048 + k), 0u);
  }

  float c_val = 0.0f;  // LSTM cell state: thread t<64 owns (b=t>>2, d=blk*4+(t&3))
  unsigned ep = 0;
  unsigned short* xc_cur = p.xc0;
  unsigned short* xc_nxt = p.xc1;
  const int aoff = (lane & 15) * KK + w * 384 + (lane >> 4) * 8;  // A-frag elem offset

  grid_barrier(p.bar, ++ep, blk);

  for (int tstep = 0; tstep < TT; ++tstep) {
    // ================= Phase A: gates MFMA + LSTM pointwise =================
    {
      const unsigned long long* xb = (const unsigned long long*)xc_cur + (aoff >> 2);
      floatx4 a0 = {0.f, 0.f, 0.f, 0.f}, a1 = {0.f, 0.f, 0.f, 0.f};
      union UF { unsigned long long u[2]; short8 s; };
      UF af[6];
#pragma unroll
      for (int ki = 0; ki < 6; ++ki) {
        af[ki].u[0] = cload_u64(xb + ki * 8);
        af[ki].u[1] = cload_u64(xb + ki * 8 + 1);
      }
#pragma unroll
      for (int ki = 0; ki < 6; ki += 2) {
        a0 = __builtin_amdgcn_mfma_f32_16x16x32_bf16(af[ki].s, bfr[ki], a0, 0, 0, 0);
        a1 = __builtin_amdgcn_mfma_f32_16x16x32_bf16(af[ki + 1].s, bfr[ki + 1], a1, 0, 0, 0);
      }
#pragma unroll
      for (int ki = 0; ki < 6; ++ki) {
        af[ki].u[0] = cload_u64(xb + (ki + 6) * 8);
        af[ki].u[1] = cload_u64(xb + (ki + 6) * 8 + 1);
      }
#pragma unroll
      for (int ki = 0; ki < 6; ki += 2) {
        a0 = __builtin_amdgcn_mfma_f32_16x16x32_bf16(af[ki].s, bfr[ki + 6], a0, 0, 0, 0);
        a1 = __builtin_amdgcn_mfma_f32_16x16x32_bf16(af[ki + 1].s, bfr[ki + 7], a1, 0, 0, 0);
      }
      a0 += a1;
#pragma unroll
      for (int reg = 0; reg < 4; ++reg)
        redC[(w * 4 + reg) * 65 + lane] = a0[reg];
    }
    __syncthreads();
    if (t < 64) {  // pointwise LSTM for (b = t>>2, dl = t&3)
      int b = t >> 2, dl = t & 3;
      float gate[4];
#pragma unroll
      for (int g = 0; g < 4; ++g) {
        int ls = (b >> 2) * 16 + (dl * 4 + g);
        float s = biasreg[g];
#pragma unroll
        for (int w2 = 0; w2 < 8; ++w2) s += redC[(w2 * 4 + (b & 3)) * 65 + ls];
        gate[g] = s;
      }
      c_val = sigf(gate[1]) * c_val + sigf(gate[0]) * tanhf(gate[2]);
      hshA[t] = sigf(gate[3]) * tanhf(c_val);
    }
    __syncthreads();
    if (t < 32) {  // packed coherent h stores: (b=t>>1, dims blk*4 + (t&1)*2 .. +2)
      int b = t >> 1, pr = t & 1;
      unsigned v = pack2bf(hshA[b * 4 + pr * 2], hshA[b * 4 + pr * 2 + 1]);
      cstore_u32((unsigned*)(xc_nxt + b * KK + 2048 + blk * 4 + pr * 2), v);
    }
    grid_barrier(p.bar, ++ep, blk);

    // ============ Phase C: phi -> window -> ctx (block (bbt,dc) local) ============
    hshu[t] = cload_u32((const unsigned*)(xc_nxt + bbt * KK + 2048) + t);
    __syncthreads();
    if (t < 384) {  // phi partials: m = t>>3, part = t&7 (128 k each)
      int m = t >> 3, part = t & 7;
      const float2* wg2 = (const float2*)(p.Wg_w + m * 1024 + part * 128);
      float s = 0.f;
#pragma unroll 8
      for (int i = 0; i < 64; ++i) {
        unsigned u = hshu[part * 64 + i];
        float2 ww = wg2[i];
        s += bf2f((unsigned short)u) * ww.x + bf2f((unsigned short)(u >> 16)) * ww.y;
      }
      php[t] = s;
    }
    __syncthreads();
    if (t < 48) {
      float s = p.Wg_b[t];
#pragma unroll
      for (int i = 0; i < 8; ++i) s += php[t * 8 + i];
      phi_s[t] = s;
    }
    __syncthreads();
    if (t == 0) {  // softmax(alpha) + exps (tiny, serial)
      float mx = -1e30f;
      for (int m = 0; m < 16; ++m) mx = fmaxf(mx, phi_s[32 + m]);
      float e[16], sum = 0.f;
      for (int m = 0; m < 16; ++m) { e[m] = __expf(phi_s[32 + m] - mx); sum += e[m]; }
      float inv = 1.0f / sum;
      for (int m = 0; m < 16; ++m) alsh[m] = e[m] * inv;
      for (int m = 0; m < 16; ++m) {
        ksish[m]  = __expf(phi_s[m]);
        invbsh[m] = __expf(-phi_s[16 + m]);
      }
    }
    __syncthreads();
    {  // R(s) = sum_m alpha*F_R(s); w(s) = R(s) - R(s-1) since F_L(s) == F_R(s-1)
      float su = (float)t;
      float rv = 0.f;
#pragma unroll
      for (int m = 0; m < 16; ++m)
        rv += alsh[m] * sigf((su + 0.5f - ksish[m]) * invbsh[m]);
      Rsh[t + 1] = rv;
      if (t == 0) {
        float r0 = 0.f;
#pragma unroll
        for (int m = 0; m < 16; ++m)
          r0 += alsh[m] * sigf((-0.5f - ksish[m]) * invbsh[m]);
        Rsh[0] = r0;
      }
    }
    __syncthreads();
    if (dc == 0) {  // alignment (+ termination = 1 - R(len-1))
      p.out[OUT_ALIGN + ((size_t)bbt * TT + tstep) * SS + t] = Rsh[t + 1] - Rsh[t];
      if (tstep == TT - 1 && t == 0) p.out[OUT_TERM + bbt] = 1.0f - Rsh[p.lens[bbt]];
    }
    if (t < 256) {  // pack w into s-pair half2
      half2v v;
      v.x = (_Float16)(Rsh[2 * t + 1] - Rsh[2 * t]);
      v.y = (_Float16)(Rsh[2 * t + 2] - Rsh[2 * t + 1]);
      wsh2[t] = v;
    }
    __syncthreads();
    {  // ctx partials: v_dot2_f32_f16 over LDS-resident memory slice
      int dl = t & 63, sp = t >> 6;
      float s = 0.f;
#pragma unroll 8
      for (int q = 0; q < 32; ++q) {
        int pr = sp * 32 + q;
        s = __builtin_amdgcn_fdot2(memsh2[pr * 64 + dl], wsh2[pr], s, false);
      }
      ctxp[sp][dl] = s;
    }
    __syncthreads();
    if (t < 64) {
      float cv = 0.f;
#pragma unroll
      for (int pp = 0; pp < 8; ++pp) cv += ctxp[pp][t];
      ctxf[t] = cv;
      if (tstep == TT - 1) p.out[bbt * DD + dc * 64 + t] = cv;
    } else if (t >= 64 && t < 96) {
      if (tstep + 1 < TT) {  // stage x_{t+1}: packed coherent stores
        int k = dc * 64 + 2 * (t - 64);
        const float* xs = p.x + (size_t)bbt * TT * DD + (size_t)(tstep + 1) * DD + k;
        cstore_u32((unsigned*)(xc_nxt + bbt * KK + k), pack2bf(xs[0], xs[1]));
      }
    }
    __syncthreads();
    if (t < 32) {  // packed coherent ctx stores
      int j = 2 * t;
      cstore_u32((unsigned*)(xc_nxt + bbt * KK + 1024 + dc * 64 + j),
                 pack2bf(ctxf[j], ctxf[j + 1]));
    }
    grid_barrier(p.bar, ++ep, blk);

    unsigned short* tmp = xc_cur; xc_cur = xc_nxt; xc_nxt = tmp;
  }
}

extern "C" void kernel_launch(void* const* d_in, const int* in_sizes, int n_in,
                              void* d_out, int out_size, void* d_ws, size_t ws_size,
                              hipStream_t stream) {
  (void)in_sizes; (void)n_in; (void)out_size; (void)ws_size;
  KParams p;
  p.x    = (const float*)d_in[0];
  p.mem  = (const float*)d_in[1];
  p.lens = (const int*)d_in[2];
  p.W_ih = (const float*)d_in[3];
  p.W_hh = (const float*)d_in[4];
  p.b_ih = (const float*)d_in[5];
  p.b_hh = (const float*)d_in[6];
  p.Wg_w = (const float*)d_in[7];
  p.Wg_b = (const float*)d_in[8];
  p.out  = (float*)d_out;
  p.bar  = (unsigned*)d_ws;
  p.xc0  = (unsigned short*)((char*)d_ws + 4096);
  p.xc1  = (unsigned short*)((char*)d_ws + 4096 + BB * KK * 2);

  hipMemsetAsync(d_ws, 0, 4096, stream);  // zero barrier counters every call

  const unsigned dynLds = 65536;  // half2 memory slice
  hipFuncSetAttribute((const void*)tts_kernel, hipFuncAttributeMaxDynamicSharedMemorySize,
                      (int)dynLds);

  void* args[] = { &p };
  hipLaunchCooperativeKernel((const void*)tts_kernel, dim3(NBLK), dim3(NTHR), args, dynLds,
                             stream);
}

// Round 6
// 18050.018 us; speedup vs baseline: 5.0395x; 1.0998x over previous
//
#include <hip/hip_runtime.h>
#include <hip/hip_fp16.h>

#define BB 16
#define TT 1024
#define DD 1024
#define SS 512
#define KK 3072   // [x | ctx | h]

#define NBLK 256
#define NTHR 512

// d_out layout (floats): context [0,16384) | alignment [16384, 8404992) | termination [8404992,+16)
#define OUT_ALIGN 16384
#define OUT_TERM  8404992

typedef __attribute__((ext_vector_type(8))) short short8;     // 8 bf16 (4 VGPRs)
typedef __attribute__((ext_vector_type(4))) float floatx4;    // MFMA C/D
typedef __attribute__((ext_vector_type(2))) _Float16 half2v;  // v_dot2 operand

struct KParams {
  const float* x;      // (B,T,D) fp32
  const float* mem;    // (B,S,D) fp32
  const int*   lens;
  const float* W_ih;   // (4D, 2D)
  const float* W_hh;   // (4D, D)
  const float* b_ih;
  const float* b_hh;
  const float* Wg_w;   // (48, D)
  const float* Wg_b;
  float* out;
  unsigned* bar;        // flag barrier region (zeroed each call)
  unsigned short* xc0;  // (B, 3072) bf16 recurrent state [x|ctx|h]
  unsigned short* xc1;
};

__device__ __forceinline__ float sigf(float v) { return 1.0f / (1.0f + __expf(-v)); }

__device__ __forceinline__ unsigned short f2bf(float f) {  // RNE fp32->bf16
  unsigned u = __float_as_uint(f);
  return (unsigned short)((u + 0x7FFFu + ((u >> 16) & 1u)) >> 16);
}
__device__ __forceinline__ float bf2f(unsigned short h) {
  return __uint_as_float(((unsigned)h) << 16);
}
__device__ __forceinline__ unsigned pack2bf(float a, float b) {
  return (unsigned)f2bf(a) | ((unsigned)f2bf(b) << 16);
}

// Agent-scope relaxed atomics = plain loads/stores with sc coherence bits (no RMW):
// rendezvous at the coherence point, bypass stale L1/L2, fully pipelined.
__device__ __forceinline__ void cstore_u32(unsigned* p2, unsigned v) {
  __hip_atomic_store(p2, v, __ATOMIC_RELAXED, __HIP_MEMORY_SCOPE_AGENT);
}
__device__ __forceinline__ unsigned cload_u32(const unsigned* p2) {
  return __hip_atomic_load(p2, __ATOMIC_RELAXED, __HIP_MEMORY_SCOPE_AGENT);
}
__device__ __forceinline__ unsigned long long cload_u64(const unsigned long long* p2) {
  return __hip_atomic_load(p2, __ATOMIC_RELAXED, __HIP_MEMORY_SCOPE_AGENT);
}

// Store-flag barrier: NO atomic RMWs (R4 evidence: contended leaf fetch_adds ~ multi-us/step).
// Each block stores its epoch to a private 128B-strided flag; block 0's threads poll all
// flags, then one release store; others spin on the release word. Monotonic epochs.
__device__ __forceinline__ void grid_barrier(unsigned* bar, unsigned ep, int blk) {
  __syncthreads();
  if (blk == 0) {
    if (threadIdx.x == 0) cstore_u32(&bar[64], ep);  // block 0's own flag (slot 0)
    if (threadIdx.x < NBLK) {
      while (cload_u32(&bar[64 + threadIdx.x * 32]) < ep) __builtin_amdgcn_s_sleep(1);
    }
    __syncthreads();  // all flags seen
    if (threadIdx.x == 0) cstore_u32(&bar[0], ep);   // release
  } else {
    if (threadIdx.x == 0) {
      cstore_u32(&bar[64 + blk * 32], ep);
      while (cload_u32(&bar[0]) < ep) __builtin_amdgcn_s_sleep(1);
    }
  }
  asm volatile("" ::: "memory");
  __syncthreads();
}

__global__ __launch_bounds__(NTHR) void tts_kernel(KParams p) {
  extern __shared__ char smem[];
  half2v* memsh2 = (half2v*)smem;  // [256 s-pairs][64 d] fp16x2, 64 KiB (R4-proven)

  __shared__ float redC[8 * 4 * 65 + 4];  // wave-partial C tiles
  __shared__ float hshA[64];              // phase-A h staging
  __shared__ unsigned hshu[8 * 65];       // phase-C h (bf16 pairs), +1 pad: bank=(part+i)%32
  __shared__ float php[384];
  __shared__ float phi_s[48];
  __shared__ float alsh[16], ksish[16], invbsh[16];
  __shared__ float Rsh[513];              // R(s), s=-1..511
  __shared__ half2v wsh2[256];            // w(s) packed in s-pairs
  __shared__ float ctxp[8][64];

  const int t    = threadIdx.x;
  const int blk  = blockIdx.x;
  const int lane = t & 63;
  const int w    = t >> 6;     // wave id [0,8): K-slice [w*384, +384)
  const int bbt  = blk & 15;   // batch this block serves in phase C
  const int dc   = blk >> 4;   // 64-wide d-chunk for ctx / x-copy

  // ---- one-time: B-fragments (weights) into registers as bf16 ----
  short8 bfr[12];
  {
    const int n = lane & 15;
    const int r = (n & 3) * 1024 + blk * 4 + (n >> 2);
    const int q = lane >> 4;
#pragma unroll
    for (int ki = 0; ki < 12; ++ki) {
      short8 v;
      const int k0 = w * 384 + ki * 32 + q * 8;
#pragma unroll
      for (int j = 0; j < 8; ++j) {
        int k = k0 + j;
        float wv = (k < 2048) ? p.W_ih[(size_t)r * 2048 + k]
                              : p.W_hh[(size_t)r * 1024 + (k - 2048)];
        v[j] = (short)f2bf(wv);
      }
      bfr[ki] = v;
    }
  }
  // ---- one-time: biases ----
  float biasreg[4] = {0.f, 0.f, 0.f, 0.f};
  if (t < 64) {
    int dl = t & 3;
#pragma unroll
    for (int g = 0; g < 4; ++g) {
      int r = g * 1024 + blk * 4 + dl;
      biasreg[g] = p.b_ih[r] + p.b_hh[r];
    }
  }
  // ---- one-time: memory[bbt, :, dc*64..+64) -> LDS as half2 s-pairs ----
  {
    int dl = t & 63, sp = t >> 6;
    for (int pr = sp; pr < 256; pr += 8) {
      const float* mp = p.mem + (size_t)bbt * SS * DD + (size_t)(2 * pr) * DD + dc * 64 + dl;
      half2v v;
      v.x = (_Float16)mp[0];
      v.y = (_Float16)mp[DD];
      memsh2[pr * 64 + dl] = v;
    }
  }
  // ---- one-time: xc0 = [x_0 | 0 | 0] ----
  if (t < 32) {
    int k = dc * 64 + 2 * t;
    const float* xs = p.x + (size_t)bbt * TT * DD + k;
    cstore_u32((unsigned*)(p.xc0 + bbt * KK + k), pack2bf(xs[0], xs[1]));
    cstore_u32((unsigned*)(p.xc0 + bbt * KK + 1024 + k), 0u);
    cstore_u32((unsigned*)(p.xc0 + bbt * KK + 2048 + k), 0u);
  }

  float c_val = 0.0f;  // LSTM cell state: thread t<64 owns (b=t>>2, d=blk*4+(t&3))
  unsigned ep = 0;
  unsigned short* xc_cur = p.xc0;
  unsigned short* xc_nxt = p.xc1;
  const int aoff = (lane & 15) * KK + w * 384 + (lane >> 4) * 8;  // A-frag elem offset

  grid_barrier(p.bar, ++ep, blk);

  for (int tstep = 0; tstep < TT; ++tstep) {
    // ================= Phase A: gates MFMA + LSTM pointwise =================
    {
      const unsigned long long* xb = (const unsigned long long*)xc_cur + (aoff >> 2);
      floatx4 a0 = {0.f, 0.f, 0.f, 0.f}, a1 = {0.f, 0.f, 0.f, 0.f};
      union UF { unsigned long long u[2]; short8 s; };
      UF af[6];
#pragma unroll
      for (int ki = 0; ki < 6; ++ki) {
        af[ki].u[0] = cload_u64(xb + ki * 8);
        af[ki].u[1] = cload_u64(xb + ki * 8 + 1);
      }
#pragma unroll
      for (int ki = 0; ki < 6; ki += 2) {
        a0 = __builtin_amdgcn_mfma_f32_16x16x32_bf16(af[ki].s, bfr[ki], a0, 0, 0, 0);
        a1 = __builtin_amdgcn_mfma_f32_16x16x32_bf16(af[ki + 1].s, bfr[ki + 1], a1, 0, 0, 0);
      }
#pragma unroll
      for (int ki = 0; ki < 6; ++ki) {
        af[ki].u[0] = cload_u64(xb + (ki + 6) * 8);
        af[ki].u[1] = cload_u64(xb + (ki + 6) * 8 + 1);
      }
#pragma unroll
      for (int ki = 0; ki < 6; ki += 2) {
        a0 = __builtin_amdgcn_mfma_f32_16x16x32_bf16(af[ki].s, bfr[ki + 6], a0, 0, 0, 0);
        a1 = __builtin_amdgcn_mfma_f32_16x16x32_bf16(af[ki + 1].s, bfr[ki + 7], a1, 0, 0, 0);
      }
      a0 += a1;
#pragma unroll
      for (int reg = 0; reg < 4; ++reg)
        redC[(w * 4 + reg) * 65 + lane] = a0[reg];
    }
    __syncthreads();
    if (t < 64) {  // pointwise LSTM for (b = t>>2, dl = t&3)
      int b = t >> 2, dl = t & 3;
      float gate[4];
#pragma unroll
      for (int g = 0; g < 4; ++g) {
        int ls = (b >> 2) * 16 + (dl * 4 + g);
        float s = biasreg[g];
#pragma unroll
        for (int w2 = 0; w2 < 8; ++w2) s += redC[(w2 * 4 + (b & 3)) * 65 + ls];
        gate[g] = s;
      }
      c_val = sigf(gate[1]) * c_val + sigf(gate[0]) * tanhf(gate[2]);
      hshA[t] = sigf(gate[3]) * tanhf(c_val);
    } else if (t >= 64 && t < 96) {
      if (tstep + 1 < TT) {  // prefetch x_{t+1} into xc_nxt (consumed after 2 barriers)
        int k = dc * 64 + 2 * (t - 64);
        const float* xs = p.x + (size_t)bbt * TT * DD + (size_t)(tstep + 1) * DD + k;
        cstore_u32((unsigned*)(xc_nxt + bbt * KK + k), pack2bf(xs[0], xs[1]));
      }
    }
    __syncthreads();
    if (t < 32) {  // packed coherent h stores
      int b = t >> 1, pr = t & 1;
      unsigned v = pack2bf(hshA[b * 4 + pr * 2], hshA[b * 4 + pr * 2 + 1]);
      cstore_u32((unsigned*)(xc_nxt + b * KK + 2048 + blk * 4 + pr * 2), v);
    }
    grid_barrier(p.bar, ++ep, blk);

    // ============ Phase C: phi -> window -> ctx (block (bbt,dc) local) ============
    // h (bf16 pairs) -> padded LDS: row part=t>>6 (64 pairs) + 1 pad word per row
    hshu[(t >> 6) * 65 + (t & 63)] = cload_u32((const unsigned*)(xc_nxt + bbt * KK + 2048) + t);
    __syncthreads();
    if (t < 384) {  // phi partials: m = t>>3, part = t&7 (128 k each)
      int m = t >> 3, part = t & 7;
      const float2* wg2 = (const float2*)(p.Wg_w + m * 1024 + part * 128);
      const unsigned* hrow = hshu + part * 65;
      float s = 0.f;
#pragma unroll 8
      for (int i = 0; i < 64; ++i) {
        unsigned u = hrow[i];
        float2 ww = wg2[i];
        s += bf2f((unsigned short)u) * ww.x + bf2f((unsigned short)(u >> 16)) * ww.y;
      }
      php[t] = s;
    }
    __syncthreads();
    if (t < 48) {
      float s = p.Wg_b[t];
#pragma unroll
      for (int i = 0; i < 8; ++i) s += php[t * 8 + i];
      phi_s[t] = s;
    }
    __syncthreads();
    if (t < 16) {  // parallel softmax + exps (lanes 0..15 of wave 0; xor stays in [0,16))
      float av = phi_s[32 + t];
      float mx = av;
#pragma unroll
      for (int o = 1; o < 16; o <<= 1) mx = fmaxf(mx, __shfl_xor(mx, o, 64));
      float e = __expf(av - mx);
      float sm = e;
#pragma unroll
      for (int o = 1; o < 16; o <<= 1) sm += __shfl_xor(sm, o, 64);
      alsh[t]   = e / sm;
      ksish[t]  = __expf(phi_s[t]);
      invbsh[t] = __expf(-phi_s[16 + t]);
    }
    __syncthreads();
    {  // R(s); w(s) = R(s) - R(s-1) since F_L(s) == F_R(s-1)
      float su = (float)t;
      float rv = 0.f;
#pragma unroll
      for (int m = 0; m < 16; ++m)
        rv += alsh[m] * sigf((su + 0.5f - ksish[m]) * invbsh[m]);
      Rsh[t + 1] = rv;
      if (t == 0) {
        float r0 = 0.f;
#pragma unroll
        for (int m = 0; m < 16; ++m)
          r0 += alsh[m] * sigf((-0.5f - ksish[m]) * invbsh[m]);
        Rsh[0] = r0;
      }
    }
    __syncthreads();
    if (dc == 0) {  // alignment (+ termination = 1 - R(len-1))
      p.out[OUT_ALIGN + ((size_t)bbt * TT + tstep) * SS + t] = Rsh[t + 1] - Rsh[t];
      if (tstep == TT - 1 && t == 0) p.out[OUT_TERM + bbt] = 1.0f - Rsh[p.lens[bbt]];
    }
    if (t < 256) {  // pack w into s-pair half2
      half2v v;
      v.x = (_Float16)(Rsh[2 * t + 1] - Rsh[2 * t]);
      v.y = (_Float16)(Rsh[2 * t + 2] - Rsh[2 * t + 1]);
      wsh2[t] = v;
    }
    __syncthreads();
    {  // ctx partials: v_dot2_f32_f16 over LDS-resident memory slice
      int dl = t & 63, sp = t >> 6;
      float s = 0.f;
#pragma unroll 8
      for (int q = 0; q < 32; ++q) {
        int pr = sp * 32 + q;
        s = __builtin_amdgcn_fdot2(memsh2[pr * 64 + dl], wsh2[pr], s, false);
      }
      ctxp[sp][dl] = s;
    }
    __syncthreads();
    if (t < 64) {
      float cv = 0.f;
#pragma unroll
      for (int pp = 0; pp < 8; ++pp) cv += ctxp[pp][t];
      if (tstep == TT - 1) p.out[bbt * DD + dc * 64 + t] = cv;
      float cvn = __shfl_down(cv, 1, 64);
      if ((t & 1) == 0)
        cstore_u32((unsigned*)(xc_nxt + bbt * KK + 1024 + dc * 64 + t), pack2bf(cv, cvn));
    }
    grid_barrier(p.bar, ++ep, blk);

    unsigned short* tmp = xc_cur; xc_cur = xc_nxt; xc_nxt = tmp;
  }
}

extern "C" void kernel_launch(void* const* d_in, const int* in_sizes, int n_in,
                              void* d_out, int out_size, void* d_ws, size_t ws_size,
                              hipStream_t stream) {
  (void)in_sizes; (void)n_in; (void)out_size; (void)ws_size;
  KParams p;
  p.x    = (const float*)d_in[0];
  p.mem  = (const float*)d_in[1];
  p.lens = (const int*)d_in[2];
  p.W_ih = (const float*)d_in[3];
  p.W_hh = (const float*)d_in[4];
  p.b_ih = (const float*)d_in[5];
  p.b_hh = (const float*)d_in[6];
  p.Wg_w = (const float*)d_in[7];
  p.Wg_b = (const float*)d_in[8];
  p.out  = (float*)d_out;
  p.bar  = (unsigned*)d_ws;
  p.xc0  = (unsigned short*)((char*)d_ws + 36864);
  p.xc1  = (unsigned short*)((char*)d_ws + 36864 + BB * KK * 2);

  hipMemsetAsync(d_ws, 0, 36864, stream);  // zero barrier flags every call

  const unsigned dynLds = 65536;  // half2 memory slice (R4-proven size)
  hipFuncSetAttribute((const void*)tts_kernel, hipFuncAttributeMaxDynamicSharedMemorySize,
                      (int)dynLds);

  void* args[] = { &p };
  hipLaunchCooperativeKernel((const void*)tts_kernel, dim3(NBLK), dim3(NTHR), args, dynLds,
                             stream);
}